// Round 7
// baseline (746.408 us; speedup 1.0000x reference)
//
#include <hip/hip_runtime.h>
#include <hip/hip_fp16.h>

#define HW 36864      // 192*192
#define IMGS 128      // B*C
#define CHUNK 64      // images per ptg chunk

typedef _Float16 h16;
typedef _Float16 v8h __attribute__((ext_vector_type(8)));
typedef _Float16 v4hh __attribute__((ext_vector_type(4)));
typedef float v4f __attribute__((ext_vector_type(4)));

static __device__ __forceinline__ int imax(int a, int b) { return a > b ? a : b; }
static __device__ __forceinline__ int imin(int a, int b) { return a < b ? a : b; }

__device__ __constant__ float LIFT_C[6] = {
  -0.5f, 0.25f,                                            // bior53
  -1.586134342f, -0.05298011854f, 0.8829110762f, 0.4435068522f  // bior97
};
__device__ __constant__ int FIR_L[4]   = {8, 12, 12, 30};
__device__ __constant__ int FIR_PA[4]  = {2, 4, 4, 13};
__device__ __constant__ int FIR_OFF[4] = {0, 8, 20, 32};

// raw (unnormalized) FIR lowpass filters concatenated: db4(8) db6(12) sym6(12) coif5(30)
__device__ constexpr float FIRC[62] = {
  -0.0105974017850021f, 0.0328830116668852f, 0.0308413818355607f, -0.1870348117188811f,
  -0.0279837694169839f, 0.6308807679295904f, 0.7148465705529155f, 0.2303778133088964f,
  0.00107730108499558f, -0.00477725751101065f, -0.0005538422009938f, 0.03158203931748603f,
  0.02752286553030533f, -0.0975016055873225f, -0.12976686756709563f, 0.22626469396544f,
  0.3152503517092432f, -0.7511339080210959f, 0.4946238903984534f, 0.1115407433501095f,
  -0.007800708325034148f, 0.001767711864242804f, 0.04472490177066578f, -0.02106029251230056f,
  -0.0726375227866f, 0.3379294217282401f, 0.787641141030194f, 0.4910559419267466f,
  -0.048311742585632f, -0.1179901111484105f, 0.00349071208421747f, 0.01540410932702737f,
  -3.459977283621256e-05f, -7.098330313814114e-05f, 0.0004662169601128863f, 0.001117518770890601f,
  -0.002574517688750223f, -0.00900797613666158f, 0.015880544863615904f, 0.03455502757306163f,
  -0.08230192710688598f, -0.07179982161931202f, 0.42848347637761874f, 0.7937772226256206f,
  0.4051769024096169f, -0.06112339000267287f, -0.06577191128185562f, 0.023452696141836267f,
  0.007782596427325418f, -0.003793512864491014f, -0.0002606761356811993f, 0.000107502882505652f,
  1.10319778524429e-05f, -5.520763127949e-06f, -1.0682196848076e-06f, 5.236425333584e-07f,
  1.125098976034e-07f, -5.417490769329e-08f, -8.8631e-09f, 4.2921e-09f, 6.7e-10f, -3.2e-10f,
};

// ---------------- gate: 1x1 conv -> relu -> 1x1 conv -> softmax -> renorm ----------------
__global__ __launch_bounds__(256) void k_gate(
    const float* __restrict__ x, const float* __restrict__ w1, const float* __restrict__ b1,
    const float* __restrict__ w2, const float* __restrict__ b2, float* __restrict__ gate)
{
  __shared__ float w1s[256], b1s[8], w2s[48], b2s[6];
  int tid = threadIdx.x;
  w1s[tid] = w1[tid];
  if (tid < 8)  b1s[tid] = b1[tid];
  if (tid < 48) w2s[tid] = w2[tid];
  if (tid < 6)  b2s[tid] = b2[tid];
  __syncthreads();
  int px = blockIdx.x * 256 + tid;        // exactly 4*HW threads
  int b = px / HW, p = px - b * HW;
  const float* xb = x + (size_t)b * 32 * HW + p;
  float xv[32];
#pragma unroll
  for (int c = 0; c < 32; ++c) xv[c] = xb[(size_t)c * HW];
  float hb[8];
#pragma unroll
  for (int j = 0; j < 8; ++j) {
    float s = b1s[j];
#pragma unroll
    for (int c = 0; c < 32; ++c) s += w1s[j * 32 + c] * xv[c];
    hb[j] = fmaxf(s, 0.f);
  }
  float e[6], mx = -1e30f;
#pragma unroll
  for (int k = 0; k < 6; ++k) {
    float s = b2s[k];
#pragma unroll
    for (int j = 0; j < 8; ++j) s += w2s[k * 8 + j] * hb[j];
    e[k] = s; mx = fmaxf(mx, s);
  }
  float se = 0.f;
#pragma unroll
  for (int k = 0; k < 6; ++k) { e[k] = expf(e[k] - mx); se += e[k]; }
  float inv = 1.f / se, s2 = 0.f;
#pragma unroll
  for (int k = 0; k < 6; ++k) { e[k] *= inv; s2 += e[k]; }
  float inv2 = 1.f / (s2 + 1e-12f);
  float* gp = gate + (size_t)b * 6 * HW + p;
#pragma unroll
  for (int k = 0; k < 6; ++k) gp[(size_t)k * HW] = e[k] * inv2;
}

// ---------------- build the 12 operator matrices (fp16, 192x192 row-major) ----------------
// mat = cand*2 + side. FIR cands 0..3: side0 = lo conv+resize, side1 = hi conv+resize.
// Lift cands 4..5: side0 = sA*approx+upsample, side1 = sD*detail+upsample.
// Built BY COLUMN: column `col` of M = the 1-D transform applied to basis vector e_col.
__global__ __launch_bounds__(64) void k_build(
    h16* __restrict__ Kall, const float* __restrict__ s53A, const float* __restrict__ s53D,
    const float* __restrict__ s97A, const float* __restrict__ s97D)
{
  const int col = blockIdx.x;      // 0..191
  const int mat = blockIdx.y;      // 0..11
  const int cand = mat >> 1, side = mat & 1;
  const int tid = threadIdx.x;
  h16* out = Kall + (size_t)mat * HW;
  if (cand < 4) {
    const int Lf = FIR_L[cand], PA = FIR_PA[cand], OFF = FIR_OFF[cand];
    float ss = 0.f;
    for (int j = 0; j < Lf; ++j) ss += FIRC[OFF + j] * FIRC[OFF + j];
    const float invn = 1.f / (sqrtf(ss) + 1e-12f);
    for (int i = tid; i < 192; i += 64) {
      const int d = (i < 96) ? 1 : 2;
      const int q0 = i - d;
      const int i0 = imax(q0, 0), i1 = imin(q0 + 1, 189);
      const float tt = (float)d - (float)(2 * i + 1) * (1.f / 192.f);
      float c0 = 0.f, c1 = 0.f;
      for (int j = 0; j < Lf; ++j) {
        float fj = side ? (((j & 1) ? -1.f : 1.f) * FIRC[OFF + Lf - 1 - j]) : FIRC[OFF + j];
        fj *= invn;
        int r0 = i0 + j - PA; r0 = r0 < 0 ? -r0 : (r0 > 191 ? 382 - r0 : r0);
        int r1 = i1 + j - PA; r1 = r1 < 0 ? -r1 : (r1 > 191 ? 382 - r1 : r1);
        if (r0 == col) c0 += fj;
        if (r1 == col) c1 += fj;
      }
      out[(size_t)i * 192 + col] = (h16)((1.f - tt) * c0 + tt * c1);
    }
  } else {
    __shared__ float yb[192];
    __shared__ float sb[96];
    yb[tid] = 0.f; yb[tid + 64] = 0.f; yb[tid + 128] = 0.f;
    __syncthreads();
    if (tid == 0) yb[col] = 1.f;
    __syncthreads();
    const int c97 = (cand == 5);
    const int base = c97 ? 2 : 0, ns = c97 ? 4 : 2;
    for (int s = 0; s < ns; ++s) {
      const float cf = LIFT_C[base + s] * 0.5f;
      for (int j = tid; j < 96; j += 64) {
        int jm = (j == 0) ? 1 : j - 1, jp = (j == 95) ? 94 : j + 1;
        if ((s & 1) == 0) yb[2 * j + 1] += cf * (yb[2 * jm] + yb[2 * jp]);
        else              yb[2 * j]     += cf * (yb[2 * jm + 1] + yb[2 * jp + 1]);
      }
      __syncthreads();
    }
    const float sA = c97 ? s97A[0] : s53A[0];
    const float sD = c97 ? s97D[0] : s53D[0];
    for (int u = tid; u < 96; u += 64)
      sb[u] = side ? sD * yb[2 * u + 1] : sA * yb[2 * u];
    __syncthreads();
    for (int i = tid; i < 192; i += 64) {
      const int u0 = (i >> 1) + (i & 1) - 1;
      const float tt = (i & 1) ? 0.25f : 0.75f;
      const int a0 = imax(u0, 0), a1 = imin(u0 + 1, 95);
      out[(size_t)i * 192 + col] = (h16)((1.f - tt) * sb[a0] + tt * sb[a1]);
    }
  }
}

// ---------------- GEMM W: PT[w'][r] = sum_w K[w'][w] * X[r][w] ----------------
// grid (6 cands, CHUNK imgs), 256 thr, dynamic LDS = X fp16 [192][200] = 76800 B.
// MFMA 16x16x32 f16; A = K (global, L2-hot), B^T = X row-major (LDS, b128-aligned).
__global__ void k_gemmW(
    const float* __restrict__ x, const h16* __restrict__ Kall,
    h16* __restrict__ ptg, int img0)
{
  extern __shared__ h16 Xs[];     // [192][200]
  const int cand = blockIdx.x;
  const int ci = blockIdx.y;
  const int img = img0 + ci;
  const int tid = threadIdx.x;
  const int lane = tid & 63, wv = tid >> 6;
  const int lm = lane & 15, quad = lane >> 4;
  // stage X -> fp16 LDS (row stride 200 halves keeps 16B alignment, breaks bank pow2)
  const float* xi = x + (size_t)img * HW;
  for (int i = tid; i < 9216; i += 256) {
    int r = i / 48, c4 = (i - r * 48) * 4;
    float4 v = *(const float4*)(xi + (size_t)r * 192 + c4);
    v4hh h; h[0] = (h16)v.x; h[1] = (h16)v.y; h[2] = (h16)v.z; h[3] = (h16)v.w;
    *(v4hh*)(Xs + (size_t)r * 200 + c4) = h;
  }
  __syncthreads();
  const int m0 = wv * 48;
  const int ktlo = imax(0, (m0 - 20) >> 5);
  const int kthi = imin(5, (m0 + 67) >> 5);
  for (int sel = 0; sel < 2; ++sel) {
    const h16* A = Kall + (size_t)(cand * 2 + sel) * HW;
    h16* P = ptg + ((size_t)(cand * 2 + sel) * CHUNK + ci) * HW;
    for (int nc = 0; nc < 3; ++nc) {
      v4f C[3][4];
#pragma unroll
      for (int mi = 0; mi < 3; ++mi)
#pragma unroll
        for (int ni = 0; ni < 4; ++ni) C[mi][ni] = (v4f){0.f, 0.f, 0.f, 0.f};
      for (int kt = ktlo; kt <= kthi; ++kt) {
        const int k0 = kt * 32 + quad * 8;
        v8h a[3], b[4];
#pragma unroll
        for (int mi = 0; mi < 3; ++mi)
          a[mi] = *(const v8h*)(A + (size_t)(m0 + mi * 16 + lm) * 192 + k0);
#pragma unroll
        for (int ni = 0; ni < 4; ++ni)
          b[ni] = *(const v8h*)(Xs + (size_t)(nc * 64 + ni * 16 + lm) * 200 + k0);
#pragma unroll
        for (int mi = 0; mi < 3; ++mi)
#pragma unroll
          for (int ni = 0; ni < 4; ++ni)
            C[mi][ni] = __builtin_amdgcn_mfma_f32_16x16x32_f16(a[mi], b[ni], C[mi][ni], 0, 0, 0);
      }
      // D: row(w') = m0+mi*16+quad*4+reg, col(r) = nc*64+ni*16+lm
#pragma unroll
      for (int mi = 0; mi < 3; ++mi) {
        const int row = m0 + mi * 16 + quad * 4;
#pragma unroll
        for (int ni = 0; ni < 4; ++ni) {
          const int colr = nc * 64 + ni * 16 + lm;
#pragma unroll
          for (int r = 0; r < 4; ++r)
            P[(size_t)(row + r) * 192 + colr] = (h16)C[mi][ni][r];
        }
      }
    }
    __syncthreads();
  }
}

// ---------------- GEMM H + gated combine over all 6 candidates ----------------
// OUT_s[h'][w'] = sum_cand gate[cand][h'][w'] * sum_h K_{cand,s&1}[h'][h] * PT_{cand,s>>1}[w'][h]
// grid (4 h-bands of 48, CHUNK imgs), 256 thr, no LDS. sf written fp16 with hf folded.
__global__ void k_gemmH(
    const h16* __restrict__ Kall, const h16* __restrict__ ptg,
    const float* __restrict__ gate, const float* __restrict__ hfp,
    h16* __restrict__ sf, int img0)
{
  const int band = blockIdx.x;
  const int ci = blockIdx.y;
  const int img = img0 + ci;
  const int bimg = img >> 5;
  const int tid = threadIdx.x;
  const int lane = tid & 63, wv = tid >> 6;
  const int lm = lane & 15, quad = lane >> 4;
  const int m0 = band * 48;
  const float hfv = hfp[0];
  const int ktlo = imax(0, (m0 - 20) >> 5);
  const int kthi = imin(5, (m0 + 67) >> 5);
  for (int ntl = 0; ntl < 3; ++ntl) {
    const int nt = wv * 3 + ntl;
    const int wcol = nt * 16 + lm;
    for (int bsel = 0; bsel < 2; ++bsel) {
      v4f acc0[3], acc1[3];
#pragma unroll
      for (int mi = 0; mi < 3; ++mi) {
        acc0[mi] = (v4f){0.f, 0.f, 0.f, 0.f};
        acc1[mi] = (v4f){0.f, 0.f, 0.f, 0.f};
      }
      for (int cand = 0; cand < 6; ++cand) {
        const h16* A0 = Kall + (size_t)(cand * 2 + 0) * HW;
        const h16* A1 = Kall + (size_t)(cand * 2 + 1) * HW;
        const h16* B = ptg + ((size_t)(cand * 2 + bsel) * CHUNK + ci) * HW + (size_t)wcol * 192;
        v4f C0[3], C1[3];
#pragma unroll
        for (int mi = 0; mi < 3; ++mi) {
          C0[mi] = (v4f){0.f, 0.f, 0.f, 0.f};
          C1[mi] = (v4f){0.f, 0.f, 0.f, 0.f};
        }
        for (int kt = ktlo; kt <= kthi; ++kt) {
          const int k0 = kt * 32 + quad * 8;
          v8h bb = *(const v8h*)(B + k0);
#pragma unroll
          for (int mi = 0; mi < 3; ++mi) {
            const size_t arow = (size_t)(m0 + mi * 16 + lm) * 192 + k0;
            v8h a0 = *(const v8h*)(A0 + arow);
            v8h a1 = *(const v8h*)(A1 + arow);
            C0[mi] = __builtin_amdgcn_mfma_f32_16x16x32_f16(a0, bb, C0[mi], 0, 0, 0);
            C1[mi] = __builtin_amdgcn_mfma_f32_16x16x32_f16(a1, bb, C1[mi], 0, 0, 0);
          }
        }
        const float* gp = gate + (size_t)(bimg * 6 + cand) * HW + wcol;
#pragma unroll
        for (int mi = 0; mi < 3; ++mi) {
          const int hrow = m0 + mi * 16 + quad * 4;
#pragma unroll
          for (int r = 0; r < 4; ++r) {
            const float g = gp[(size_t)(hrow + r) * 192];
            acc0[mi][r] += g * C0[mi][r];
            acc1[mi][r] += g * C1[mi][r];
          }
        }
      }
      const float f0 = (bsel == 0) ? 1.f : hfv;    // s=0 no hf; s=1,2,3 get hf
      h16* out0 = sf + ((size_t)img * 4 + 2 * bsel) * HW;
      h16* out1 = sf + ((size_t)img * 4 + 2 * bsel + 1) * HW;
#pragma unroll
      for (int mi = 0; mi < 3; ++mi) {
        const int hrow = m0 + mi * 16 + quad * 4;
#pragma unroll
        for (int r = 0; r < 4; ++r) {
          out0[(size_t)(hrow + r) * 192 + wcol] = (h16)(acc0[mi][r] * f0);
          out1[(size_t)(hrow + r) * 192 + wcol] = (h16)(acc1[mi][r] * hfv);
        }
      }
    }
  }
}

// ---------------- final 1x1 projection 128 -> 32 ----------------
__global__ __launch_bounds__(256) void k_proj(
    const h16* __restrict__ sf, const float* __restrict__ pw,
    const float* __restrict__ pb, float* __restrict__ out)
{
  const int tid = threadIdx.x;
  const int lane = tid & 63;
  const int og = __builtin_amdgcn_readfirstlane(tid >> 6);   // 0..3, wave-uniform scalar
  const int b = blockIdx.x / 576;                             // 576 blocks per image
  const int p = blockIdx.x * 64 - b * HW + lane;
  const h16* sfb = sf + (size_t)(b * 128) * HW + p;
  const float* pwb = pw + og * 8 * 128;                       // scalar base
  float acc[8];
#pragma unroll
  for (int oo = 0; oo < 8; ++oo) acc[oo] = 0.f;
#pragma unroll 4
  for (int ch = 0; ch < 128; ++ch) {
    const float v = (float)sfb[(size_t)ch * HW];
#pragma unroll
    for (int oo = 0; oo < 8; ++oo) acc[oo] = fmaf(pwb[oo * 128 + ch], v, acc[oo]);
  }
#pragma unroll
  for (int oo = 0; oo < 8; ++oo) {
    out[(size_t)(b * 32 + og * 8 + oo) * HW + p] = acc[oo] + pb[og * 8 + oo];
  }
}

extern "C" void kernel_launch(void* const* d_in, const int* in_sizes, int n_in,
                              void* d_out, int out_size, void* d_ws, size_t ws_size,
                              hipStream_t stream) {
  (void)in_sizes; (void)n_in; (void)out_size; (void)ws_size;
  const float* x    = (const float*)d_in[0];
  const float* gw1  = (const float*)d_in[1];
  const float* gb1  = (const float*)d_in[2];
  const float* gw2  = (const float*)d_in[3];
  const float* gb2  = (const float*)d_in[4];
  const float* s53A = (const float*)d_in[5];
  const float* s53D = (const float*)d_in[6];
  const float* s97A = (const float*)d_in[7];
  const float* s97D = (const float*)d_in[8];
  const float* hfp  = (const float*)d_in[9];
  const float* pw   = (const float*)d_in[10];
  const float* pb   = (const float*)d_in[11];
  float* out = (float*)d_out;

  // workspace layout (bytes):
  //   gate fp32:        0 ..  3,538,944
  //   Kall fp16:  3,538,944 ..  4,423,680   (12 x 192 x 192)
  //   ptg  fp16:  4,423,680 .. 61,046,784   (12 x CHUNK x 192 x 192)
  //   sf   fp16: 61,046,784 .. 98,795,520   (128 x 4 x 192 x 192)
  float* gate = (float*)d_ws;
  h16* Kall = (h16*)((char*)d_ws + 3538944);
  h16* ptg  = (h16*)((char*)d_ws + 4423680);
  h16* sf   = (h16*)((char*)d_ws + 61046784);

  hipLaunchKernelGGL(k_gate, dim3(576), dim3(256), 0, stream, x, gw1, gb1, gw2, gb2, gate);
  hipLaunchKernelGGL(k_build, dim3(192, 12), dim3(64), 0, stream, Kall, s53A, s53D, s97A, s97D);
  for (int chunk = 0; chunk < 2; ++chunk) {
    const int img0 = chunk * CHUNK;
    hipLaunchKernelGGL(k_gemmW, dim3(6, CHUNK), dim3(256), 76800, stream, x, Kall, ptg, img0);
    hipLaunchKernelGGL(k_gemmH, dim3(4, CHUNK), dim3(256), 0, stream, Kall, ptg, gate, hfp, sf, img0);
  }
  hipLaunchKernelGGL(k_proj, dim3(2304), dim3(256), 0, stream, sf, pw, pb, out);
}

// Round 8
// 419.973 us; speedup vs baseline: 1.7773x; 1.7773x over previous
//
#include <hip/hip_runtime.h>
#include <hip/hip_fp16.h>

#define HW 36864      // 192*192
#define IMGS 128      // B*C
#define CHUNK 32      // images per chunk (= one batch b)

typedef _Float16 h16;
typedef _Float16 v8h __attribute__((ext_vector_type(8)));
typedef float v4f __attribute__((ext_vector_type(4)));

static __device__ __forceinline__ int imax(int a, int b) { return a > b ? a : b; }
static __device__ __forceinline__ int imin(int a, int b) { return a < b ? a : b; }

__device__ __constant__ float LIFT_C[6] = {
  -0.5f, 0.25f,                                            // bior53
  -1.586134342f, -0.05298011854f, 0.8829110762f, 0.4435068522f  // bior97
};
__device__ __constant__ int FIR_L[4]   = {8, 12, 12, 30};
__device__ __constant__ int FIR_PA[4]  = {2, 4, 4, 13};
__device__ __constant__ int FIR_OFF[4] = {0, 8, 20, 32};

// raw (unnormalized) FIR lowpass filters concatenated: db4(8) db6(12) sym6(12) coif5(30)
__device__ constexpr float FIRC[62] = {
  -0.0105974017850021f, 0.0328830116668852f, 0.0308413818355607f, -0.1870348117188811f,
  -0.0279837694169839f, 0.6308807679295904f, 0.7148465705529155f, 0.2303778133088964f,
  0.00107730108499558f, -0.00477725751101065f, -0.0005538422009938f, 0.03158203931748603f,
  0.02752286553030533f, -0.0975016055873225f, -0.12976686756709563f, 0.22626469396544f,
  0.3152503517092432f, -0.7511339080210959f, 0.4946238903984534f, 0.1115407433501095f,
  -0.007800708325034148f, 0.001767711864242804f, 0.04472490177066578f, -0.02106029251230056f,
  -0.0726375227866f, 0.3379294217282401f, 0.787641141030194f, 0.4910559419267466f,
  -0.048311742585632f, -0.1179901111484105f, 0.00349071208421747f, 0.01540410932702737f,
  -3.459977283621256e-05f, -7.098330313814114e-05f, 0.0004662169601128863f, 0.001117518770890601f,
  -0.002574517688750223f, -0.00900797613666158f, 0.015880544863615904f, 0.03455502757306163f,
  -0.08230192710688598f, -0.07179982161931202f, 0.42848347637761874f, 0.7937772226256206f,
  0.4051769024096169f, -0.06112339000267287f, -0.06577191128185562f, 0.023452696141836267f,
  0.007782596427325418f, -0.003793512864491014f, -0.0002606761356811993f, 0.000107502882505652f,
  1.10319778524429e-05f, -5.520763127949e-06f, -1.0682196848076e-06f, 5.236425333584e-07f,
  1.125098976034e-07f, -5.417490769329e-08f, -8.8631e-09f, 4.2921e-09f, 6.7e-10f, -3.2e-10f,
};

// ---------------- gate: 1x1 conv -> relu -> 1x1 conv -> softmax -> renorm ----------------
__global__ __launch_bounds__(256) void k_gate(
    const float* __restrict__ x, const float* __restrict__ w1, const float* __restrict__ b1,
    const float* __restrict__ w2, const float* __restrict__ b2, float* __restrict__ gate)
{
  __shared__ float w1s[256], b1s[8], w2s[48], b2s[6];
  int tid = threadIdx.x;
  w1s[tid] = w1[tid];
  if (tid < 8)  b1s[tid] = b1[tid];
  if (tid < 48) w2s[tid] = w2[tid];
  if (tid < 6)  b2s[tid] = b2[tid];
  __syncthreads();
  int px = blockIdx.x * 256 + tid;        // exactly 4*HW threads
  int b = px / HW, p = px - b * HW;
  const float* xb = x + (size_t)b * 32 * HW + p;
  float xv[32];
#pragma unroll
  for (int c = 0; c < 32; ++c) xv[c] = xb[(size_t)c * HW];
  float hb[8];
#pragma unroll
  for (int j = 0; j < 8; ++j) {
    float s = b1s[j];
#pragma unroll
    for (int c = 0; c < 32; ++c) s += w1s[j * 32 + c] * xv[c];
    hb[j] = fmaxf(s, 0.f);
  }
  float e[6], mx = -1e30f;
#pragma unroll
  for (int k = 0; k < 6; ++k) {
    float s = b2s[k];
#pragma unroll
    for (int j = 0; j < 8; ++j) s += w2s[k * 8 + j] * hb[j];
    e[k] = s; mx = fmaxf(mx, s);
  }
  float se = 0.f;
#pragma unroll
  for (int k = 0; k < 6; ++k) { e[k] = expf(e[k] - mx); se += e[k]; }
  float inv = 1.f / se, s2 = 0.f;
#pragma unroll
  for (int k = 0; k < 6; ++k) { e[k] *= inv; s2 += e[k]; }
  float inv2 = 1.f / (s2 + 1e-12f);
  float* gp = gate + (size_t)b * 6 * HW + p;
#pragma unroll
  for (int k = 0; k < 6; ++k) gp[(size_t)k * HW] = e[k] * inv2;
}

// ---------------- build the 12 operator matrices (fp16, 192x192 row-major [out][in]) ----------------
__global__ __launch_bounds__(64) void k_build(
    h16* __restrict__ Kall, const float* __restrict__ s53A, const float* __restrict__ s53D,
    const float* __restrict__ s97A, const float* __restrict__ s97D)
{
  const int col = blockIdx.x;      // 0..191 (input index)
  const int mat = blockIdx.y;      // 0..11
  const int cand = mat >> 1, side = mat & 1;
  const int tid = threadIdx.x;
  h16* out = Kall + (size_t)mat * HW;
  if (cand < 4) {
    const int Lf = FIR_L[cand], PA = FIR_PA[cand], OFF = FIR_OFF[cand];
    float ss = 0.f;
    for (int j = 0; j < Lf; ++j) ss += FIRC[OFF + j] * FIRC[OFF + j];
    const float invn = 1.f / (sqrtf(ss) + 1e-12f);
    for (int i = tid; i < 192; i += 64) {
      const int d = (i < 96) ? 1 : 2;
      const int q0 = i - d;
      const int i0 = imax(q0, 0), i1 = imin(q0 + 1, 189);
      const float tt = (float)d - (float)(2 * i + 1) * (1.f / 192.f);
      float c0 = 0.f, c1 = 0.f;
      for (int j = 0; j < Lf; ++j) {
        float fj = side ? (((j & 1) ? -1.f : 1.f) * FIRC[OFF + Lf - 1 - j]) : FIRC[OFF + j];
        fj *= invn;
        int r0 = i0 + j - PA; r0 = r0 < 0 ? -r0 : (r0 > 191 ? 382 - r0 : r0);
        int r1 = i1 + j - PA; r1 = r1 < 0 ? -r1 : (r1 > 191 ? 382 - r1 : r1);
        if (r0 == col) c0 += fj;
        if (r1 == col) c1 += fj;
      }
      out[(size_t)i * 192 + col] = (h16)((1.f - tt) * c0 + tt * c1);
    }
  } else {
    __shared__ float yb[192];
    __shared__ float sb[96];
    yb[tid] = 0.f; yb[tid + 64] = 0.f; yb[tid + 128] = 0.f;
    __syncthreads();
    if (tid == 0) yb[col] = 1.f;
    __syncthreads();
    const int c97 = (cand == 5);
    const int base = c97 ? 2 : 0, ns = c97 ? 4 : 2;
    for (int s = 0; s < ns; ++s) {
      const float cf = LIFT_C[base + s] * 0.5f;
      for (int j = tid; j < 96; j += 64) {
        int jm = (j == 0) ? 1 : j - 1, jp = (j == 95) ? 94 : j + 1;
        if ((s & 1) == 0) yb[2 * j + 1] += cf * (yb[2 * jm] + yb[2 * jp]);
        else              yb[2 * j]     += cf * (yb[2 * jm + 1] + yb[2 * jp + 1]);
      }
      __syncthreads();
    }
    const float sA = c97 ? s97A[0] : s53A[0];
    const float sD = c97 ? s97D[0] : s53D[0];
    for (int u = tid; u < 96; u += 64)
      sb[u] = side ? sD * yb[2 * u + 1] : sA * yb[2 * u];
    __syncthreads();
    for (int i = tid; i < 192; i += 64) {
      const int u0 = (i >> 1) + (i & 1) - 1;
      const float tt = (i & 1) ? 0.25f : 0.75f;
      const int a0 = imax(u0, 0), a1 = imin(u0 + 1, 95);
      out[(size_t)i * 192 + col] = (h16)((1.f - tt) * sb[a0] + tt * sb[a1]);
    }
  }
}

// ---------------- pass W: P[plane][ci][h][w'] = sum_w Kall[plane][w'][w] * X[img][h][w] ----------------
// grid (2 img-halves x 12 planes, CHUNK), 384 thr (6 waves). A = X half staged fp16 LDS;
// B = Kall rows from global (L2-hot, identical addrs across img blocks). Banded K (+-24 reach).
__global__ __launch_bounds__(384) void k_gw(
    const float* __restrict__ x, const h16* __restrict__ Kall,
    h16* __restrict__ P, int img0)
{
  __shared__ h16 As[96 * 200];
  const int bx = blockIdx.x;
  const int plane = bx % 12, half = bx / 12;
  const int ci = blockIdx.y;
  const int img = img0 + ci;
  const int tid = threadIdx.x;
  const float* xi = x + (size_t)img * HW + (size_t)half * 96 * 192;
  for (int u = tid; u < 2304; u += 384) {        // u = c8*96 + r (bank-friendly)
    int c8 = u / 96, r = u - c8 * 96;
    float4 v0 = *(const float4*)(xi + (size_t)r * 192 + c8 * 8);
    float4 v1 = *(const float4*)(xi + (size_t)r * 192 + c8 * 8 + 4);
    v8h h;
    h[0] = (h16)v0.x; h[1] = (h16)v0.y; h[2] = (h16)v0.z; h[3] = (h16)v0.w;
    h[4] = (h16)v1.x; h[5] = (h16)v1.y; h[6] = (h16)v1.z; h[7] = (h16)v1.w;
    *(v8h*)(As + (size_t)r * 200 + c8 * 8) = h;
  }
  __syncthreads();
  const int lane = tid & 63, wv = tid >> 6;       // 6 waves, 16 m-rows each
  const int lm = lane & 15, quad = lane >> 4;
  const h16* KB = Kall + (size_t)plane * HW;
  h16* Pp = P + ((size_t)plane * CHUNK + ci) * HW;
  const int mrow = wv * 16;
  for (int nt = 0; nt < 12; ++nt) {
    const int n0 = nt * 16;
    const int ktlo = imax(0, (n0 - 24) >> 5), kthi = imin(5, (n0 + 39) >> 5);
    v4f C = (v4f){0.f, 0.f, 0.f, 0.f};
    for (int kt = ktlo; kt <= kthi; ++kt) {
      const int k0 = kt * 32 + quad * 8;
      v8h a = *(const v8h*)(As + (size_t)(mrow + lm) * 200 + k0);
      v8h b = *(const v8h*)(KB + (size_t)(n0 + lm) * 192 + k0);
      C = __builtin_amdgcn_mfma_f32_16x16x32_f16(a, b, C, 0, 0, 0);
    }
    const int hg = half * 96 + mrow + quad * 4;
    const int wc = n0 + lm;
#pragma unroll
    for (int r = 0; r < 4; ++r)
      Pp[(size_t)(hg + r) * 192 + wc] = (h16)C[r];
  }
}

// ---------------- pass H: OUT[cand*4+sw*2+sh][ci][h'][w'] = sum_h Kall[cand*2+sh][h'][h]*P[...][h][w'] ----------------
// grid (2 n-halves x 12 pw-planes, CHUNK), 256 thr (4 waves). B = P transposed into LDS
// ([w'][h], paired-row b32 writes); A = Kall rows global. Both sh computed per block.
__global__ __launch_bounds__(256) void k_gh(
    const h16* __restrict__ Kall, const h16* __restrict__ P,
    h16* __restrict__ OUT)
{
  __shared__ h16 Bs[96 * 200];
  const int bx = blockIdx.x;
  const int plane = bx % 12, nh = bx / 12;
  const int ci = blockIdx.y;
  const int tid = threadIdx.x;
  const h16* Pp = P + ((size_t)plane * CHUNK + ci) * HW;
  // transpose-stage: task u = wg*96 + hp (lanes sweep hp -> 2-way-max bank aliasing)
  for (int u = tid; u < 1152; u += 256) {
    int wg = u / 96, hp = u - wg * 96;
    int w0 = nh * 96 + wg * 8;
    v8h r0 = *(const v8h*)(Pp + (size_t)(2 * hp) * 192 + w0);
    v8h r1 = *(const v8h*)(Pp + (size_t)(2 * hp + 1) * 192 + w0);
#pragma unroll
    for (int j = 0; j < 8; ++j) {
      union { h16 h[2]; unsigned int u32; } pk;
      pk.h[0] = r0[j]; pk.h[1] = r1[j];
      *(unsigned int*)(Bs + (size_t)(wg * 8 + j) * 200 + 2 * hp) = pk.u32;
    }
  }
  __syncthreads();
  const int lane = tid & 63, wv = tid >> 6;
  const int lm = lane & 15, quad = lane >> 4;
  const int cand = plane >> 1, sw = plane & 1;
  for (int sh = 0; sh < 2; ++sh) {
    const h16* KB = Kall + (size_t)(cand * 2 + sh) * HW;
    h16* Op = OUT + ((size_t)(cand * 4 + sw * 2 + sh) * CHUNK + ci) * HW;
    for (int mi = 0; mi < 3; ++mi) {
      const int m0 = (wv * 3 + mi) * 16;
      const int ktlo = imax(0, (m0 - 24) >> 5), kthi = imin(5, (m0 + 39) >> 5);
      v4f C[6];
#pragma unroll
      for (int nt = 0; nt < 6; ++nt) C[nt] = (v4f){0.f, 0.f, 0.f, 0.f};
      for (int kt = ktlo; kt <= kthi; ++kt) {
        const int k0 = kt * 32 + quad * 8;
        v8h a = *(const v8h*)(KB + (size_t)(m0 + lm) * 192 + k0);
#pragma unroll
        for (int nt = 0; nt < 6; ++nt) {
          v8h b = *(const v8h*)(Bs + (size_t)(nt * 16 + lm) * 200 + k0);
          C[nt] = __builtin_amdgcn_mfma_f32_16x16x32_f16(a, b, C[nt], 0, 0, 0);
        }
      }
      const int hr = m0 + quad * 4;
#pragma unroll
      for (int nt = 0; nt < 6; ++nt) {
        const int wc = nh * 96 + nt * 16 + lm;
#pragma unroll
        for (int r = 0; r < 4; ++r)
          Op[(size_t)(hr + r) * 192 + wc] = (h16)C[nt][r];
      }
    }
  }
}

// ---------------- gate-combine + 1x1 projection, one chunk (= one batch b) ----------------
// out[o][p] = pb[o] + sum_c sum_s pw[o][c*4+s] * (hf_s * sum_cand g[cand][p]*OUT[cand*4+s][c][p])
__global__ __launch_bounds__(256) void k_proj2(
    const h16* __restrict__ OUT, const float* __restrict__ gate, const float* __restrict__ hfp,
    const float* __restrict__ pw, const float* __restrict__ pb, float* __restrict__ out, int b)
{
  const int tid = threadIdx.x;
  const int lane = tid & 63;
  const int og = __builtin_amdgcn_readfirstlane(tid >> 6);
  const int p = blockIdx.x * 64 + lane;
  float g[6];
#pragma unroll
  for (int cand = 0; cand < 6; ++cand)
    g[cand] = gate[(size_t)(b * 6 + cand) * HW + p];
  const float hfv = hfp[0];
  const float* pwb = pw + og * 8 * 128;
  float acc[8];
#pragma unroll
  for (int o = 0; o < 8; ++o) acc[o] = 0.f;
  const size_t SP = (size_t)CHUNK * HW;     // plane stride
  for (int c = 0; c < 32; ++c) {
    float sf0 = 0.f, sf1 = 0.f, sf2 = 0.f, sf3 = 0.f;
#pragma unroll
    for (int cand = 0; cand < 6; ++cand) {
      const h16* Ob = OUT + ((size_t)(cand * 4) * CHUNK + c) * HW + p;
      sf0 += g[cand] * (float)Ob[0];
      sf1 += g[cand] * (float)Ob[SP];
      sf2 += g[cand] * (float)Ob[2 * SP];
      sf3 += g[cand] * (float)Ob[3 * SP];
    }
    sf1 *= hfv; sf2 *= hfv; sf3 *= hfv;
#pragma unroll
    for (int o = 0; o < 8; ++o) {
      const float* pr = pwb + o * 128 + c * 4;
      acc[o] += pr[0] * sf0 + pr[1] * sf1 + pr[2] * sf2 + pr[3] * sf3;
    }
  }
#pragma unroll
  for (int o = 0; o < 8; ++o)
    out[(size_t)(b * 32 + og * 8 + o) * HW + p] = acc[o] + pb[og * 8 + o];
}

extern "C" void kernel_launch(void* const* d_in, const int* in_sizes, int n_in,
                              void* d_out, int out_size, void* d_ws, size_t ws_size,
                              hipStream_t stream) {
  (void)in_sizes; (void)n_in; (void)out_size; (void)ws_size;
  const float* x    = (const float*)d_in[0];
  const float* gw1  = (const float*)d_in[1];
  const float* gb1  = (const float*)d_in[2];
  const float* gw2  = (const float*)d_in[3];
  const float* gb2  = (const float*)d_in[4];
  const float* s53A = (const float*)d_in[5];
  const float* s53D = (const float*)d_in[6];
  const float* s97A = (const float*)d_in[7];
  const float* s97D = (const float*)d_in[8];
  const float* hfp  = (const float*)d_in[9];
  const float* pw   = (const float*)d_in[10];
  const float* pb   = (const float*)d_in[11];
  float* out = (float*)d_out;

  // workspace (bytes):
  //   gate fp32:         0 ..  3,538,944
  //   Kall fp16:  3,538,944 ..  4,423,680   (12 x 192 x 192)
  //   P    fp16:  4,423,680 .. 32,735,232   (12 x 32 x 192 x 192)
  //   OUT  fp16: 32,735,232 .. 89,358,336   (24 x 32 x 192 x 192)
  float* gate = (float*)d_ws;
  h16* Kall = (h16*)((char*)d_ws + 3538944);
  h16* P    = (h16*)((char*)d_ws + 4423680);
  h16* OUT  = (h16*)((char*)d_ws + 32735232);

  hipLaunchKernelGGL(k_gate, dim3(576), dim3(256), 0, stream, x, gw1, gb1, gw2, gb2, gate);
  hipLaunchKernelGGL(k_build, dim3(192, 12), dim3(64), 0, stream, Kall, s53A, s53D, s97A, s97D);
  for (int chunk = 0; chunk < 4; ++chunk) {
    const int img0 = chunk * CHUNK;
    hipLaunchKernelGGL(k_gw, dim3(24, CHUNK), dim3(384), 0, stream, x, Kall, P, img0);
    hipLaunchKernelGGL(k_gh, dim3(24, CHUNK), dim3(256), 0, stream, Kall, P, OUT);
    hipLaunchKernelGGL(k_proj2, dim3(576), dim3(256), 0, stream, OUT, gate, hfp, pw, pb, out, chunk);
  }
}

// Round 9
// 369.828 us; speedup vs baseline: 2.0183x; 1.1356x over previous
//
#include <hip/hip_runtime.h>
#include <hip/hip_fp16.h>

#define HW 36864      // 192*192
#define IMGS 128      // B*C

typedef _Float16 h16;
typedef _Float16 v8h __attribute__((ext_vector_type(8)));
typedef float v4f __attribute__((ext_vector_type(4)));

static __device__ __forceinline__ int imax(int a, int b) { return a > b ? a : b; }
static __device__ __forceinline__ int imin(int a, int b) { return a < b ? a : b; }

__device__ __constant__ float LIFT_C[6] = {
  -0.5f, 0.25f,                                            // bior53
  -1.586134342f, -0.05298011854f, 0.8829110762f, 0.4435068522f  // bior97
};
__device__ __constant__ int FIR_L[4]   = {8, 12, 12, 30};
__device__ __constant__ int FIR_PA[4]  = {2, 4, 4, 13};
__device__ __constant__ int FIR_OFF[4] = {0, 8, 20, 32};

// raw (unnormalized) FIR lowpass filters concatenated: db4(8) db6(12) sym6(12) coif5(30)
__device__ constexpr float FIRC[62] = {
  -0.0105974017850021f, 0.0328830116668852f, 0.0308413818355607f, -0.1870348117188811f,
  -0.0279837694169839f, 0.6308807679295904f, 0.7148465705529155f, 0.2303778133088964f,
  0.00107730108499558f, -0.00477725751101065f, -0.0005538422009938f, 0.03158203931748603f,
  0.02752286553030533f, -0.0975016055873225f, -0.12976686756709563f, 0.22626469396544f,
  0.3152503517092432f, -0.7511339080210959f, 0.4946238903984534f, 0.1115407433501095f,
  -0.007800708325034148f, 0.001767711864242804f, 0.04472490177066578f, -0.02106029251230056f,
  -0.0726375227866f, 0.3379294217282401f, 0.787641141030194f, 0.4910559419267466f,
  -0.048311742585632f, -0.1179901111484105f, 0.00349071208421747f, 0.01540410932702737f,
  -3.459977283621256e-05f, -7.098330313814114e-05f, 0.0004662169601128863f, 0.001117518770890601f,
  -0.002574517688750223f, -0.00900797613666158f, 0.015880544863615904f, 0.03455502757306163f,
  -0.08230192710688598f, -0.07179982161931202f, 0.42848347637761874f, 0.7937772226256206f,
  0.4051769024096169f, -0.06112339000267287f, -0.06577191128185562f, 0.023452696141836267f,
  0.007782596427325418f, -0.003793512864491014f, -0.0002606761356811993f, 0.000107502882505652f,
  1.10319778524429e-05f, -5.520763127949e-06f, -1.0682196848076e-06f, 5.236425333584e-07f,
  1.125098976034e-07f, -5.417490769329e-08f, -8.8631e-09f, 4.2921e-09f, 6.7e-10f, -3.2e-10f,
};

// ---------------- gate: 1x1 conv -> relu -> 1x1 conv -> softmax -> renorm (fp16 out) ----------------
__global__ __launch_bounds__(256) void k_gate(
    const float* __restrict__ x, const float* __restrict__ w1, const float* __restrict__ b1,
    const float* __restrict__ w2, const float* __restrict__ b2, h16* __restrict__ gate)
{
  __shared__ float w1s[256], b1s[8], w2s[48], b2s[6];
  int tid = threadIdx.x;
  w1s[tid] = w1[tid];
  if (tid < 8)  b1s[tid] = b1[tid];
  if (tid < 48) w2s[tid] = w2[tid];
  if (tid < 6)  b2s[tid] = b2[tid];
  __syncthreads();
  int px = blockIdx.x * 256 + tid;        // exactly 4*HW threads
  int b = px / HW, p = px - b * HW;
  const float* xb = x + (size_t)b * 32 * HW + p;
  float xv[32];
#pragma unroll
  for (int c = 0; c < 32; ++c) xv[c] = xb[(size_t)c * HW];
  float hb[8];
#pragma unroll
  for (int j = 0; j < 8; ++j) {
    float s = b1s[j];
#pragma unroll
    for (int c = 0; c < 32; ++c) s += w1s[j * 32 + c] * xv[c];
    hb[j] = fmaxf(s, 0.f);
  }
  float e[6], mx = -1e30f;
#pragma unroll
  for (int k = 0; k < 6; ++k) {
    float s = b2s[k];
#pragma unroll
    for (int j = 0; j < 8; ++j) s += w2s[k * 8 + j] * hb[j];
    e[k] = s; mx = fmaxf(mx, s);
  }
  float se = 0.f;
#pragma unroll
  for (int k = 0; k < 6; ++k) { e[k] = expf(e[k] - mx); se += e[k]; }
  float inv = 1.f / se, s2 = 0.f;
#pragma unroll
  for (int k = 0; k < 6; ++k) { e[k] *= inv; s2 += e[k]; }
  float inv2 = 1.f / (s2 + 1e-12f);
  h16* gp = gate + (size_t)b * 6 * HW + p;
#pragma unroll
  for (int k = 0; k < 6; ++k) gp[(size_t)k * HW] = (h16)(e[k] * inv2);
}

// ---------------- build the 12 operator matrices (fp16, 192x192 row-major [out][in]) ----------------
__global__ __launch_bounds__(64) void k_build(
    h16* __restrict__ Kall, const float* __restrict__ s53A, const float* __restrict__ s53D,
    const float* __restrict__ s97A, const float* __restrict__ s97D)
{
  const int col = blockIdx.x;      // 0..191 (input index)
  const int mat = blockIdx.y;      // 0..11
  const int cand = mat >> 1, side = mat & 1;
  const int tid = threadIdx.x;
  h16* out = Kall + (size_t)mat * HW;
  if (cand < 4) {
    const int Lf = FIR_L[cand], PA = FIR_PA[cand], OFF = FIR_OFF[cand];
    float ss = 0.f;
    for (int j = 0; j < Lf; ++j) ss += FIRC[OFF + j] * FIRC[OFF + j];
    const float invn = 1.f / (sqrtf(ss) + 1e-12f);
    for (int i = tid; i < 192; i += 64) {
      const int d = (i < 96) ? 1 : 2;
      const int q0 = i - d;
      const int i0 = imax(q0, 0), i1 = imin(q0 + 1, 189);
      const float tt = (float)d - (float)(2 * i + 1) * (1.f / 192.f);
      float c0 = 0.f, c1 = 0.f;
      for (int j = 0; j < Lf; ++j) {
        float fj = side ? (((j & 1) ? -1.f : 1.f) * FIRC[OFF + Lf - 1 - j]) : FIRC[OFF + j];
        fj *= invn;
        int r0 = i0 + j - PA; r0 = r0 < 0 ? -r0 : (r0 > 191 ? 382 - r0 : r0);
        int r1 = i1 + j - PA; r1 = r1 < 0 ? -r1 : (r1 > 191 ? 382 - r1 : r1);
        if (r0 == col) c0 += fj;
        if (r1 == col) c1 += fj;
      }
      out[(size_t)i * 192 + col] = (h16)((1.f - tt) * c0 + tt * c1);
    }
  } else {
    __shared__ float yb[192];
    __shared__ float sb[96];
    yb[tid] = 0.f; yb[tid + 64] = 0.f; yb[tid + 128] = 0.f;
    __syncthreads();
    if (tid == 0) yb[col] = 1.f;
    __syncthreads();
    const int c97 = (cand == 5);
    const int base = c97 ? 2 : 0, ns = c97 ? 4 : 2;
    for (int s = 0; s < ns; ++s) {
      const float cf = LIFT_C[base + s] * 0.5f;
      for (int j = tid; j < 96; j += 64) {
        int jm = (j == 0) ? 1 : j - 1, jp = (j == 95) ? 94 : j + 1;
        if ((s & 1) == 0) yb[2 * j + 1] += cf * (yb[2 * jm] + yb[2 * jp]);
        else              yb[2 * j]     += cf * (yb[2 * jm + 1] + yb[2 * jp + 1]);
      }
      __syncthreads();
    }
    const float sA = c97 ? s97A[0] : s53A[0];
    const float sD = c97 ? s97D[0] : s53D[0];
    for (int u = tid; u < 96; u += 64)
      sb[u] = side ? sD * yb[2 * u + 1] : sA * yb[2 * u];
    __syncthreads();
    for (int i = tid; i < 192; i += 64) {
      const int u0 = (i >> 1) + (i & 1) - 1;
      const float tt = (i & 1) ? 0.25f : 0.75f;
      const int a0 = imax(u0, 0), a1 = imin(u0 + 1, 95);
      out[(size_t)i * 192 + col] = (h16)((1.f - tt) * sb[a0] + tt * sb[a1]);
    }
  }
}

// ---------------- pass W: P[plane][img][h][w'] = sum_w Kall[plane][w'][w] * X[img][h][w] ----------------
// grid (24, 128) = 3072 blocks, 384 thr (6 waves). A = X half staged fp16 LDS;
// B = Kall rows from global (L2-hot). Banded K (+-24 reach).
__global__ __launch_bounds__(384) void k_gw(
    const float* __restrict__ x, const h16* __restrict__ Kall, h16* __restrict__ P)
{
  __shared__ h16 As[96 * 200];
  const int bx = blockIdx.x;
  const int plane = bx % 12, half = bx / 12;
  const int img = blockIdx.y;
  const int tid = threadIdx.x;
  const float* xi = x + (size_t)img * HW + (size_t)half * 96 * 192;
  for (int u = tid; u < 2304; u += 384) {        // u = c8*96 + r (bank-friendly)
    int c8 = u / 96, r = u - c8 * 96;
    float4 v0 = *(const float4*)(xi + (size_t)r * 192 + c8 * 8);
    float4 v1 = *(const float4*)(xi + (size_t)r * 192 + c8 * 8 + 4);
    v8h h;
    h[0] = (h16)v0.x; h[1] = (h16)v0.y; h[2] = (h16)v0.z; h[3] = (h16)v0.w;
    h[4] = (h16)v1.x; h[5] = (h16)v1.y; h[6] = (h16)v1.z; h[7] = (h16)v1.w;
    *(v8h*)(As + (size_t)r * 200 + c8 * 8) = h;
  }
  __syncthreads();
  const int lane = tid & 63, wv = tid >> 6;       // 6 waves, 16 m-rows each
  const int lm = lane & 15, quad = lane >> 4;
  const h16* KB = Kall + (size_t)plane * HW;
  h16* Pp = P + ((size_t)plane * IMGS + img) * HW;
  const int mrow = wv * 16;
  for (int nt = 0; nt < 12; ++nt) {
    const int n0 = nt * 16;
    const int ktlo = imax(0, (n0 - 24) >> 5), kthi = imin(5, (n0 + 39) >> 5);
    v4f C = (v4f){0.f, 0.f, 0.f, 0.f};
    for (int kt = ktlo; kt <= kthi; ++kt) {
      const int k0 = kt * 32 + quad * 8;
      v8h a = *(const v8h*)(As + (size_t)(mrow + lm) * 200 + k0);
      v8h b = *(const v8h*)(KB + (size_t)(n0 + lm) * 192 + k0);
      C = __builtin_amdgcn_mfma_f32_16x16x32_f16(a, b, C, 0, 0, 0);
    }
    const int hg = half * 96 + mrow + quad * 4;
    const int wc = n0 + lm;
#pragma unroll
    for (int r = 0; r < 4; ++r)
      Pp[(size_t)(hg + r) * 192 + wc] = (h16)C[r];
  }
}

// ---------------- pass H + gated combine: sf[img][sw*2+sh] = sum_cand g*K_sh·P[cand,sw] ----------------
// grid (8 = sw x 4 w'-quarters, 128 imgs), 256 thr (4 waves). Per cand: stage P-slice
// transposed in LDS ([w'][h], paired-row b32), both sh GEMMs, gate-weighted accumulate.
__global__ __launch_bounds__(256) void k_gh2(
    const h16* __restrict__ Kall, const h16* __restrict__ P, const h16* __restrict__ gate,
    const float* __restrict__ hfp, h16* __restrict__ sf)
{
  __shared__ h16 Bs[48 * 200];
  const int bx = blockIdx.x;
  const int sw = bx & 1, qt = bx >> 1;
  const int img = blockIdx.y;
  const int bimg = img >> 5;
  const int tid = threadIdx.x;
  const int lane = tid & 63, wv = tid >> 6;
  const int lm = lane & 15, quad = lane >> 4;
  const int w0q = qt * 48;
  v4f acc[2][3][3];
#pragma unroll
  for (int sh = 0; sh < 2; ++sh)
#pragma unroll
    for (int mi = 0; mi < 3; ++mi)
#pragma unroll
      for (int nt = 0; nt < 3; ++nt) acc[sh][mi][nt] = (v4f){0.f, 0.f, 0.f, 0.f};

  for (int cand = 0; cand < 6; ++cand) {
    __syncthreads();   // previous cand's Bs reads done
    const h16* Pp = P + ((size_t)(cand * 2 + sw) * IMGS + img) * HW;
    for (int u = tid; u < 576; u += 256) {      // wg 0..5 (8-col groups), hp 0..95 (row pairs)
      int wg = u / 96, hp = u - wg * 96;
      int w0 = w0q + wg * 8;
      v8h r0 = *(const v8h*)(Pp + (size_t)(2 * hp) * 192 + w0);
      v8h r1 = *(const v8h*)(Pp + (size_t)(2 * hp + 1) * 192 + w0);
#pragma unroll
      for (int j = 0; j < 8; ++j) {
        union { h16 h[2]; unsigned int u32; } pk;
        pk.h[0] = r0[j]; pk.h[1] = r1[j];
        *(unsigned int*)(Bs + (size_t)(wg * 8 + j) * 200 + 2 * hp) = pk.u32;
      }
    }
    __syncthreads();
    const h16* g16 = gate + (size_t)(bimg * 6 + cand) * HW;
    for (int mi = 0; mi < 3; ++mi) {
      const int m0 = wv * 48 + mi * 16;
      const int ktlo = imax(0, (m0 - 24) >> 5), kthi = imin(5, (m0 + 39) >> 5);
      const int hr0 = m0 + quad * 4;
      float g[3][4];
#pragma unroll
      for (int nt = 0; nt < 3; ++nt)
#pragma unroll
        for (int r = 0; r < 4; ++r)
          g[nt][r] = (float)g16[(size_t)(hr0 + r) * 192 + w0q + nt * 16 + lm];
#pragma unroll
      for (int sh = 0; sh < 2; ++sh) {
        const h16* KB = Kall + (size_t)(cand * 2 + sh) * HW;
        v4f C[3];
#pragma unroll
        for (int nt = 0; nt < 3; ++nt) C[nt] = (v4f){0.f, 0.f, 0.f, 0.f};
        for (int kt = ktlo; kt <= kthi; ++kt) {
          const int k0 = kt * 32 + quad * 8;
          v8h a = *(const v8h*)(KB + (size_t)(m0 + lm) * 192 + k0);
#pragma unroll
          for (int nt = 0; nt < 3; ++nt) {
            v8h b = *(const v8h*)(Bs + (size_t)(nt * 16 + lm) * 200 + k0);
            C[nt] = __builtin_amdgcn_mfma_f32_16x16x32_f16(a, b, C[nt], 0, 0, 0);
          }
        }
#pragma unroll
        for (int nt = 0; nt < 3; ++nt)
#pragma unroll
          for (int r = 0; r < 4; ++r)
            acc[sh][mi][nt][r] += g[nt][r] * C[nt][r];
      }
    }
  }
  // epilogue: hf fold + fp16 store
  const float hfv = hfp[0];
#pragma unroll
  for (int sh = 0; sh < 2; ++sh) {
    const int s = sw * 2 + sh;
    const float f = (s == 0) ? 1.f : hfv;
    h16* Op = sf + ((size_t)img * 4 + s) * HW;
#pragma unroll
    for (int mi = 0; mi < 3; ++mi) {
      const int hr0 = wv * 48 + mi * 16 + quad * 4;
#pragma unroll
      for (int nt = 0; nt < 3; ++nt) {
        const int wc = w0q + nt * 16 + lm;
#pragma unroll
        for (int r = 0; r < 4; ++r)
          Op[(size_t)(hr0 + r) * 192 + wc] = (h16)(f * acc[sh][mi][nt][r]);
      }
    }
  }
}

// ---------------- final 1x1 projection 128 -> 32 ----------------
__global__ __launch_bounds__(256) void k_proj(
    const h16* __restrict__ sf, const float* __restrict__ pw,
    const float* __restrict__ pb, float* __restrict__ out)
{
  const int tid = threadIdx.x;
  const int lane = tid & 63;
  const int og = __builtin_amdgcn_readfirstlane(tid >> 6);   // 0..3, wave-uniform scalar
  const int b = blockIdx.x / 576;                             // 576 blocks per image
  const int p = blockIdx.x * 64 - b * HW + lane;
  const h16* sfb = sf + (size_t)(b * 128) * HW + p;
  const float* pwb = pw + og * 8 * 128;                       // scalar base
  float acc[8];
#pragma unroll
  for (int oo = 0; oo < 8; ++oo) acc[oo] = 0.f;
#pragma unroll 4
  for (int ch = 0; ch < 128; ++ch) {
    const float v = (float)sfb[(size_t)ch * HW];
#pragma unroll
    for (int oo = 0; oo < 8; ++oo) acc[oo] = fmaf(pwb[oo * 128 + ch], v, acc[oo]);
  }
#pragma unroll
  for (int oo = 0; oo < 8; ++oo) {
    out[(size_t)(b * 32 + og * 8 + oo) * HW + p] = acc[oo] + pb[og * 8 + oo];
  }
}

extern "C" void kernel_launch(void* const* d_in, const int* in_sizes, int n_in,
                              void* d_out, int out_size, void* d_ws, size_t ws_size,
                              hipStream_t stream) {
  (void)in_sizes; (void)n_in; (void)out_size; (void)ws_size;
  const float* x    = (const float*)d_in[0];
  const float* gw1  = (const float*)d_in[1];
  const float* gb1  = (const float*)d_in[2];
  const float* gw2  = (const float*)d_in[3];
  const float* gb2  = (const float*)d_in[4];
  const float* s53A = (const float*)d_in[5];
  const float* s53D = (const float*)d_in[6];
  const float* s97A = (const float*)d_in[7];
  const float* s97D = (const float*)d_in[8];
  const float* hfp  = (const float*)d_in[9];
  const float* pw   = (const float*)d_in[10];
  const float* pb   = (const float*)d_in[11];
  float* out = (float*)d_out;

  // workspace (bytes), total 153,649,152 (< R6's proven 154,533,888):
  //   gate fp16:          0 ..   1,769,472   (4 x 6 x HW)
  //   Kall fp16:  1,769,472 ..   2,654,208   (12 x 192 x 192)
  //   P    fp16:  2,654,208 .. 115,900,416   (12 x 128 x HW)
  //   sf   fp16: 115,900,416 .. 153,649,152  (128 x 4 x HW)
  h16* gate = (h16*)d_ws;
  h16* Kall = (h16*)((char*)d_ws + 1769472);
  h16* P    = (h16*)((char*)d_ws + 2654208);
  h16* sf   = (h16*)((char*)d_ws + 115900416);

  hipLaunchKernelGGL(k_gate, dim3(576), dim3(256), 0, stream, x, gw1, gb1, gw2, gb2, gate);
  hipLaunchKernelGGL(k_build, dim3(192, 12), dim3(64), 0, stream, Kall, s53A, s53D, s97A, s97D);
  hipLaunchKernelGGL(k_gw, dim3(24, IMGS), dim3(384), 0, stream, x, Kall, P);
  hipLaunchKernelGGL(k_gh2, dim3(8, IMGS), dim3(256), 0, stream, Kall, P, gate, hfp, sf);
  hipLaunchKernelGGL(k_proj, dim3(2304), dim3(256), 0, stream, sf, pw, pb, out);
}